// Round 15
// baseline (128.452 us; speedup 1.0000x reference)
//
#include <hip/hip_runtime.h>
#include <stdint.h>

#define NR 8192
#define DIM 512
#define BT 128             // block tile M=N
#define BK 32              // K-tile (LDS rows are 64 B = 4 x 16B chunks)
#define NT (DIM / BK)      // 16 K-tiles

typedef unsigned short u16;
typedef __attribute__((ext_vector_type(8))) __bf16 bf16x8;
typedef __attribute__((ext_vector_type(4))) float f32x4;

static __device__ __forceinline__ u16 f2bf(float f) {
    union { float f; uint32_t u; } v; v.f = f;
    uint32_t u = v.u;
    u += 0x7FFFu + ((u >> 16) & 1u);   // RNE
    return (u16)(u >> 16);
}

static __device__ __forceinline__ void gload_lds16(const void* g, void* l) {
    __builtin_amdgcn_global_load_lds(
        (__attribute__((address_space(1))) void*)(void*)g,
        (__attribute__((address_space(3))) void*)l,
        16, 0, 0);
}

// One block per row: reciprocal norms, exact fp32 diag term, fp32->bf16
// conversion, and zero rowsum for this call.
__global__ void prep_kernel(const float* __restrict__ xi, const float* __restrict__ xj,
                            u16* __restrict__ xib, u16* __restrict__ xjb,
                            float* __restrict__ inv_ni, float* __restrict__ inv_nj,
                            float* __restrict__ diag, float* __restrict__ rowsum) {
    const int row = blockIdx.x;
    const int t = threadIdx.x;                 // 128 threads, 4 elems each
    const float4 a = ((const float4*)(xi + (size_t)row * DIM))[t];
    const float4 b = ((const float4*)(xj + (size_t)row * DIM))[t];

    float ssi = a.x*a.x + a.y*a.y + a.z*a.z + a.w*a.w;
    float ssj = b.x*b.x + b.y*b.y + b.z*b.z + b.w*b.w;
    float dot = a.x*b.x + a.y*b.y + a.z*b.z + a.w*b.w;

    ushort4 av = { f2bf(a.x), f2bf(a.y), f2bf(a.z), f2bf(a.w) };
    ushort4 bv = { f2bf(b.x), f2bf(b.y), f2bf(b.z), f2bf(b.w) };
    ((ushort4*)(xib + (size_t)row * DIM))[t] = av;
    ((ushort4*)(xjb + (size_t)row * DIM))[t] = bv;

    #pragma unroll
    for (int m = 32; m >= 1; m >>= 1) {
        ssi += __shfl_xor(ssi, m, 64);
        ssj += __shfl_xor(ssj, m, 64);
        dot += __shfl_xor(dot, m, 64);
    }
    __shared__ float red[6];
    const int wave = t >> 6, lane = t & 63;
    if (lane == 0) { red[wave*3+0] = ssi; red[wave*3+1] = ssj; red[wave*3+2] = dot; }
    __syncthreads();
    if (t == 0) {
        float si = red[0] + red[3];
        float sj = red[1] + red[4];
        float d  = red[2] + red[5];
        float ini = rsqrtf(fmaxf(si, 1e-30f));
        float inj = rsqrtf(fmaxf(sj, 1e-30f));
        inv_ni[row] = ini;
        inv_nj[row] = inj;
        diag[row] = d * ini * inj;
        rowsum[row] = 0.0f;
    }
}

// Fused NT-GEMM + exp + row-sum. R7's winning shape (128x128 tile, 4 waves
// 2x2, 64x64 wave tile, 16x16x32 MFMA, 32 KB LDS, ~4 blocks/CU TLP) with
// the staging drain moved off the critical path: BK=32 double-buffer.
// Per tile: STAGE(t+1 -> other buf) issued FIRST, then 8 ds_read + 16
// MFMA (~700 cy), then one __syncthreads -- the drain waits on loads
// issued a full compute-phase earlier. Parity race-free; swizzle key for
// 64B rows: phys_chunk = c ^ ((row>>1)&3) -> 2 lanes/slot (free).
__global__ __launch_bounds__(256, 4)
void gemm_rowsum(const u16* __restrict__ A, const u16* __restrict__ B,
                 const float* __restrict__ inv_ni, const float* __restrict__ inv_nj,
                 float* __restrict__ rowsum) {
    __shared__ __align__(16) u16 ldsA[2][BT * BK];   // 2 x 8 KB
    __shared__ __align__(16) u16 ldsB[2][BT * BK];   // 2 x 8 KB

    const int tid = threadIdx.x;
    // XCD-aware, L2-aware: xcd owns 8 row-panels; concurrent blocks/XCD
    // cover 8 row-panels x ~16 col-panels: A 1MB + B 2MB < 4MB per-XCD L2.
    const int orig = blockIdx.x;
    const int xcd = orig & 7, kidx = orig >> 3;   // kidx 0..511
    const int by = xcd * 8 + (kidx & 7);          // 0..63
    const int bx = kidx >> 3;                     // 0..63
    const int row0 = by * BT, col0 = bx * BT;

    // ---- staging: pass i covers row (i*64 + (tid>>2)), phys chunk tid&3 ----
    // LDS byte = i*4096 + tid*16 (linear); global logical chunk =
    // phys ^ ((row>>1)&3); invariant across passes (64 % 8 == 0 rows).
    const int st_row = tid >> 2;                        // 0..63
    const int st_lc  = (tid & 3) ^ ((st_row >> 1) & 3); // logical 16B k-chunk
    const u16* gA = A + (size_t)(row0 + st_row) * DIM + st_lc * 8;
    const u16* gB = B + (size_t)(col0 + st_row) * DIM + st_lc * 8;
    char* const dA = (char*)ldsA + tid * 16;            // + p*8192, + i*4096
    char* const dB = (char*)ldsB + tid * 16;

    // ---- fragment reads: lane (lr,lk) -> row m*16+lr, logical chunk lk ----
    const int lane = tid & 63;
    const int lr = lane & 15, lk = lane >> 4;
    const int cb = ((lk ^ ((lr >> 1) & 3))) * 16;       // phys byte in 64B row
    const int wid = tid >> 6;
    const int wm = wid >> 1, wn = wid & 1;              // 2x2 waves, 64x64 tile
    const char* const aR = (const char*)ldsA + (wm * 64 + lr) * 64 + cb;
    const char* const bR = (const char*)ldsB + (wn * 64 + lr) * 64 + cb;

    f32x4 acc[4][4] = {};

#define STAGE(P, TN) do {                                                      \
    gload_lds16(gA + (TN) * BK,            dA + (P) * 8192);                   \
    gload_lds16(gA + (TN) * BK + 64 * DIM, dA + (P) * 8192 + 4096);            \
    gload_lds16(gB + (TN) * BK,            dB + (P) * 8192);                   \
    gload_lds16(gB + (TN) * BK + 64 * DIM, dB + (P) * 8192 + 4096);            \
} while (0)

    // ---- prologue: stage tile 0 into buf 0 ----
    STAGE(0, 0);
    __syncthreads();

    #pragma unroll 1
    for (int t = 0; t < NT; ++t) {
        const int p = t & 1;
        if (t < NT - 1) STAGE(p ^ 1, t + 1);   // issue-early: full-tile cover

        const char* aP = aR + p * 8192;
        const char* bP = bR + p * 8192;
        bf16x8 af[4], bg[4];
        #pragma unroll
        for (int m = 0; m < 4; ++m)
            af[m] = *(const bf16x8*)(aP + m * 1024);
        #pragma unroll
        for (int n = 0; n < 4; ++n)
            bg[n] = *(const bf16x8*)(bP + n * 1024);
        #pragma unroll
        for (int m = 0; m < 4; ++m)
            #pragma unroll
            for (int n = 0; n < 4; ++n)
                acc[m][n] = __builtin_amdgcn_mfma_f32_16x16x32_bf16(
                    af[m], bg[n], acc[m][n], 0, 0, 0);

        __syncthreads();                       // drain lands late; cheap
    }
#undef STAGE

    // ---- epilogue: cosine scale, exp, row-reduce, one atomic per row ----
    float inj[4];
    #pragma unroll
    for (int n = 0; n < 4; ++n)
        inj[n] = inv_nj[col0 + wn * 64 + n * 16 + lr];

    #pragma unroll
    for (int m = 0; m < 4; ++m) {
        #pragma unroll
        for (int e = 0; e < 4; ++e) {
            const int row = row0 + wm * 64 + m * 16 + lk * 4 + e;
            const float ini = inv_ni[row];
            float s = 0.0f;
            #pragma unroll
            for (int n = 0; n < 4; ++n)
                s += __expf(acc[m][n][e] * ini * inj[n]);
            s += __shfl_xor(s, 1, 64);
            s += __shfl_xor(s, 2, 64);
            s += __shfl_xor(s, 4, 64);
            s += __shfl_xor(s, 8, 64);
            if (lr == 0)
                atomicAdd(&rowsum[row], s);
        }
    }
}

__global__ void finalize(const float* __restrict__ rowsum,
                         const float* __restrict__ diag,
                         float* __restrict__ out) {
    const float E1 = 2.7182818284590452f;  // exp(1/TAU)
    float acc = 0.0f;
    for (int i = threadIdx.x; i < NR; i += 256)
        acc += __logf(rowsum[i] - E1) - diag[i];
    #pragma unroll
    for (int m = 32; m >= 1; m >>= 1)
        acc += __shfl_xor(acc, m, 64);
    __shared__ float red[4];
    const int wave = threadIdx.x >> 6, lane = threadIdx.x & 63;
    if (lane == 0) red[wave] = acc;
    __syncthreads();
    if (threadIdx.x == 0)
        out[0] = (red[0] + red[1] + red[2] + red[3]) * (1.0f / NR);
}

extern "C" void kernel_launch(void* const* d_in, const int* in_sizes, int n_in,
                              void* d_out, int out_size, void* d_ws, size_t ws_size,
                              hipStream_t stream) {
    const float* xi = (const float*)d_in[0];
    const float* xj = (const float*)d_in[1];

    char* ws = (char*)d_ws;
    u16* xib = (u16*)ws;                                // 8 MB
    u16* xjb = xib + (size_t)NR * DIM;                  // 8 MB
    float* inv_ni = (float*)(xjb + (size_t)NR * DIM);   // 32 KB
    float* inv_nj = inv_ni + NR;
    float* diag   = inv_nj + NR;
    float* rowsum = diag + NR;

    prep_kernel<<<NR, 128, 0, stream>>>(xi, xj, xib, xjb, inv_ni, inv_nj, diag, rowsum);
    gemm_rowsum<<<(NR / BT) * (NR / BT), 256, 0, stream>>>(xib, xjb, inv_ni, inv_nj, rowsum);
    finalize<<<1, 256, 0, stream>>>(rowsum, diag, (float*)d_out);
}